// Round 2
// baseline (504.350 us; speedup 1.0000x reference)
//
#include <hip/hip_runtime.h>

// Problem constants (fixed by the reference setup)
#define BB 32
#define SS 25
#define CC 64
#define HW 1764            // 42*42
#define CHUNKS (HW / 4)    // 441 float4 chunks per (b,s) spatial plane
#define TOTAL (BB * SS * CHUNKS)  // 352800 float4 outputs

__global__ __launch_bounds__(256) void eucl_kernel(
    const float* __restrict__ x1,   // [B, C, h, w]
    const float* __restrict__ x2,   // [B, S, C, h, w]
    float* __restrict__ out)        // [B, S*h*w] == [B, S, h, w] flat
{
    for (int idx = blockIdx.x * blockDim.x + threadIdx.x;
         idx < TOTAL;
         idx += gridDim.x * blockDim.x) {

        int chunk = idx % CHUNKS;       // which group of 4 spatial positions
        int bs    = idx / CHUNKS;       // combined (b,s) index
        int b     = bs / SS;

        // float4-typed bases; c-stride is HW floats = CHUNKS float4s.
        // 7056 B and chunk*16 B are both multiples of 16 -> aligned.
        const float4* __restrict__ x2p =
            reinterpret_cast<const float4*>(x2 + (size_t)bs * CC * HW) + chunk;
        const float4* __restrict__ x1p =
            reinterpret_cast<const float4*>(x1 + (size_t)b * CC * HW) + chunk;

        float4 acc = make_float4(0.f, 0.f, 0.f, 0.f);

        #pragma unroll 16
        for (int c = 0; c < CC; ++c) {
            float4 a = x1p[c * CHUNKS];
            float4 v = x2p[c * CHUNKS];
            float d0 = a.x - v.x;
            float d1 = a.y - v.y;
            float d2 = a.z - v.z;
            float d3 = a.w - v.w;
            acc.x = fmaf(d0, d0, acc.x);
            acc.y = fmaf(d1, d1, acc.y);
            acc.z = fmaf(d2, d2, acc.z);
            acc.w = fmaf(d3, d3, acc.w);
        }

        float4 r;
        r.x = sqrtf(acc.x);
        r.y = sqrtf(acc.y);
        r.z = sqrtf(acc.z);
        r.w = sqrtf(acc.w);

        // out float4 index == idx (out is [B,S,hw] flat; idx = bs*CHUNKS + chunk)
        reinterpret_cast<float4*>(out)[idx] = r;
    }
}

extern "C" void kernel_launch(void* const* d_in, const int* in_sizes, int n_in,
                              void* d_out, int out_size, void* d_ws, size_t ws_size,
                              hipStream_t stream) {
    const float* x1 = (const float*)d_in[0];
    const float* x2 = (const float*)d_in[1];
    float* out = (float*)d_out;

    const int threads = 256;
    const int blocks = (TOTAL + threads - 1) / threads;  // 1379
    eucl_kernel<<<blocks, threads, 0, stream>>>(x1, x2, out);
}

// Round 4
// 482.630 us; speedup vs baseline: 1.0450x; 1.0450x over previous
//
#include <hip/hip_runtime.h>

// Problem constants (fixed by the reference setup)
#define BB 32
#define SS 25
#define CC 64
#define HW 1764            // 42*42
#define CHUNKS (HW / 4)    // 441 float4 chunks per (b,s) spatial plane
#define TOTAL (BB * SS * CHUNKS)  // 352800 float4 outputs

typedef float v4f __attribute__((ext_vector_type(4)));

__global__ __launch_bounds__(256, 4) void eucl_kernel(
    const float* __restrict__ x1,   // [B, C, h, w]
    const float* __restrict__ x2,   // [B, S, C, h, w]
    float* __restrict__ out)        // [B, S*h*w] == [B, S, h, w] flat
{
    int idx = blockIdx.x * blockDim.x + threadIdx.x;
    if (idx >= TOTAL) return;

    int chunk = idx % CHUNKS;       // which group of 4 contiguous spatial positions
    int bs    = idx / CHUNKS;       // combined (b,s) index
    int b     = bs / SS;

    // v4f-typed bases; c-stride is HW floats = CHUNKS v4f's.
    // 7056 B and chunk*16 B are both multiples of 16 -> aligned.
    const v4f* __restrict__ x2v =
        reinterpret_cast<const v4f*>(x2 + (size_t)bs * CC * HW) + chunk;
    const v4f* __restrict__ x1v =
        reinterpret_cast<const v4f*>(x1 + (size_t)b * CC * HW) + chunk;

    v4f acc = (v4f)(0.0f);

    #pragma unroll 8
    for (int c = 0; c < CC; ++c) {
        v4f a = x1v[c * CHUNKS];                                  // cached: 25x reuse via L2
        v4f v = __builtin_nontemporal_load(&x2v[c * CHUNKS]);     // streaming: no reuse
        v4f d = a - v;
        acc = d * d + acc;   // elementwise fmac
    }

    v4f r;
    r.x = sqrtf(acc.x);
    r.y = sqrtf(acc.y);
    r.z = sqrtf(acc.z);
    r.w = sqrtf(acc.w);

    // out v4f index == idx (out is [B,S,hw] flat; idx = bs*CHUNKS + chunk)
    __builtin_nontemporal_store(r, reinterpret_cast<v4f*>(out) + idx);
}

extern "C" void kernel_launch(void* const* d_in, const int* in_sizes, int n_in,
                              void* d_out, int out_size, void* d_ws, size_t ws_size,
                              hipStream_t stream) {
    const float* x1 = (const float*)d_in[0];
    const float* x2 = (const float*)d_in[1];
    float* out = (float*)d_out;

    const int threads = 256;
    const int blocks = (TOTAL + threads - 1) / threads;  // 1379
    eucl_kernel<<<blocks, threads, 0, stream>>>(x1, x2, out);
}